// Round 12
// baseline (98.585 us; speedup 1.0000x reference)
//
#include <hip/hip_runtime.h>
#include <math.h>
#include <stdint.h>

#define NCLS 128
constexpr float ALPHA = 0.5f;
constexpr float BETA_ = 0.5f;
constexpr float EPS_ = 1e-9f;

// ws layout: gL[128] double | gce double | gcnt[128] uint | done uint  = 1548 B
__global__ void zero_ws(uint32_t* __restrict__ ws) {
    const int t = threadIdx.x;               // 256 threads, 387 words
    if (t < 387) ws[t] = 0u;
    if (t + 256 < 387) ws[t + 256] = 0u;
}

// Streaming, 2048 blocks x 4 waves = 8 waves/SIMD resident (launch_bounds 256,8).
// Wave group = 16 contiguous pairs (32 consecutive rows). Per iter: 4 independent
// 1KB loads, 16 expf, 4 interleaved 5-step xor-reduce chains. Per-row scalar math
// (log/exp/div/atomics) DEFERRED: tuples buffered in wave-private LDS, then 32
// rows processed in one 32-lane-parallel pass. Finalize fused via done-counter.
__global__ __launch_bounds__(256, 8) void loss_main(
    const float* __restrict__ y_pred,
    const int*   __restrict__ y_true,
    double* __restrict__ gL, unsigned* __restrict__ gcnt,
    double* __restrict__ gce, unsigned* __restrict__ done,
    float* __restrict__ out, int nrows, int nblocks)
{
    __shared__ float    sL[NCLS];
    __shared__ unsigned scnt[NCLS];
    __shared__ float    sce;
    __shared__ float    rb[4][32][4];      // wave-private row tuples {S,e0,tv,label}
    __shared__ int      amlast;

    const int t = threadIdx.x, w = t >> 6, lane = t & 63;
    const int half = lane >> 5, l32 = lane & 31;
    if (t == 0) sce = 0.f;
    if (t < NCLS) { sL[t] = 0.f; scnt[t] = 0u; }
    __syncthreads();

    const int wgl = blockIdx.x * 4 + w;
    const int nW  = gridDim.x * 4;
    const int nPairs = nrows >> 1;
    float ce_local = 0.f;

    for (long g0 = (long)wgl * 16; g0 + 15 < nPairs; g0 += (long)nW * 16) {
        #pragma unroll
        for (int it = 0; it < 4; ++it) {
            const long pbase = g0 + it * 4;
            float4 v[4]; int lab[4]; float S[4], tv[4];
            const float* base = y_pred + ((size_t)(pbase << 1) + half) * NCLS + (l32 << 2);
            #pragma unroll
            for (int u = 0; u < 4; ++u) {
                v[u]   = *reinterpret_cast<const float4*>(base + (size_t)(u << 1) * NCLS);
                lab[u] = y_true[((pbase + u) << 1) + half];
            }
            #pragma unroll
            for (int u = 0; u < 4; ++u) {
                const float ex = __expf(v[u].x), ey = __expf(v[u].y);
                const float ez = __expf(v[u].z), ew = __expf(v[u].w);
                S[u] = (ex + ey) + (ez + ew);
            }
            #pragma unroll
            for (int off = 16; off; off >>= 1) {
                #pragma unroll
                for (int u = 0; u < 4; ++u) S[u] += __shfl_xor(S[u], off);
            }
            #pragma unroll
            for (int u = 0; u < 4; ++u) {
                const int ls = lab[u] & 3;
                const float vs = (ls == 0) ? v[u].x : (ls == 1) ? v[u].y
                               : (ls == 2) ? v[u].z : v[u].w;
                tv[u] = __shfl(vs, (half << 5) + (lab[u] >> 2));
            }
            if (l32 == 0) {
                #pragma unroll
                for (int u = 0; u < 4; ++u) {
                    const int rl = (((it << 2) + u) << 1) + half;   // 0..31
                    rb[w][rl][0] = S[u];
                    rb[w][rl][1] = __expf(v[u].x);                  // exp(col 0)
                    rb[w][rl][2] = tv[u];
                    rb[w][rl][3] = __int_as_float(lab[u]);
                }
            }
        }
        // deferred epilogue: 32 rows in parallel on lanes 0..31 (same wave, DS in-order)
        if (lane < 32) {
            const float4 rr = *reinterpret_cast<const float4*>(rb[w][lane]);
            const int lb = __float_as_int(rr.w);
            ce_local += rr.z - __logf(rr.x);
            const float p1 = rr.y / rr.x;
            const float contrib = (lb == 0) ? ALPHA * __logf(p1 + EPS_)
                                            : __logf(1.f - p1 + EPS_);
            atomicAdd(&sL[lb], contrib);
            atomicAdd(&scnt[lb], 1u);
        }
    }

    // tail: leftover pairs + odd row, block 0 wave 0 only (empty when 32 | nrows)
    if (wgl == 0) {
        for (int p = nPairs & ~15; p < nPairs; ++p) {
            const int row = (p << 1) + half;
            const float4 v = *reinterpret_cast<const float4*>(
                y_pred + (size_t)row * NCLS + (l32 << 2));
            const int lab = y_true[row];
            const float ex = __expf(v.x), ey = __expf(v.y);
            const float ez = __expf(v.z), ew = __expf(v.w);
            float S = (ex + ey) + (ez + ew);
            #pragma unroll
            for (int off = 16; off; off >>= 1) S += __shfl_xor(S, off);
            const int ls = lab & 3;
            const float vs = (ls == 0) ? v.x : (ls == 1) ? v.y : (ls == 2) ? v.z : v.w;
            const float tv = __shfl(vs, (half << 5) + (lab >> 2));
            if (l32 == 0) {
                ce_local += tv - __logf(S);
                const float p1 = ex / S;
                const float contrib = (lab == 0) ? ALPHA * __logf(p1 + EPS_)
                                                 : __logf(1.f - p1 + EPS_);
                atomicAdd(&sL[lab], contrib);
                atomicAdd(&scnt[lab], 1u);
            }
        }
        if (nrows & 1) {
            const int row = nrows - 1;
            const float4 v = *reinterpret_cast<const float4*>(
                y_pred + (size_t)row * NCLS + (l32 << 2));
            const int lab = y_true[row];
            const float ex = __expf(v.x), ey = __expf(v.y);
            const float ez = __expf(v.z), ew = __expf(v.w);
            float S = (ex + ey) + (ez + ew);
            #pragma unroll
            for (int off = 16; off; off >>= 1) S += __shfl_xor(S, off);
            const int ls = lab & 3;
            const float vs = (ls == 0) ? v.x : (ls == 1) ? v.y : (ls == 2) ? v.z : v.w;
            const float tv = __shfl(vs, (half << 5) + (lab >> 2));
            if (lane == 0) {
                ce_local += tv - __logf(S);
                const float p1 = ex / S;
                const float contrib = (lab == 0) ? ALPHA * __logf(p1 + EPS_)
                                                 : __logf(1.f - p1 + EPS_);
                atomicAdd(&sL[lab], contrib);
                atomicAdd(&scnt[lab], 1u);
            }
        }
    }

    float lp = ce_local;
    #pragma unroll
    for (int off = 32; off; off >>= 1) lp += __shfl_xor(lp, off);
    if (lane == 0) atomicAdd(&sce, lp);
    __syncthreads();

    // block flush (rotated class order to stagger per-address contention)
    if (t < NCLS) {
        const int c = (t + blockIdx.x) & (NCLS - 1);
        if (scnt[c]) {
            atomicAdd(&gL[c], (double)sL[c]);
            atomicAdd(&gcnt[c], scnt[c]);
        }
    }
    if (t == 0) atomicAdd(gce, (double)sce);
    __syncthreads();   // implicit vmcnt(0): block's atomics performed

    if (t == 0) {
        __threadfence();
        const unsigned old = atomicAdd(done, 1u);
        amlast = (old == (unsigned)(nblocks - 1));
    }
    __syncthreads();

    if (amlast && t < 64) {
        const double c0 = (double)__hip_atomic_load(&gcnt[0], __ATOMIC_RELAXED,
                                                    __HIP_MEMORY_SCOPE_AGENT);
        const double denom = (double)nrows - c0;
        double local = 0.0;
        for (int c = t; c < NCLS; c += 64) {
            const double Lc = __hip_atomic_load(&gL[c], __ATOMIC_RELAXED,
                                                __HIP_MEMORY_SCOPE_AGENT);
            if (c == 0) local += Lc;                       // ALPHA pre-applied
            else {
                const double nc = (double)__hip_atomic_load(&gcnt[c], __ATOMIC_RELAXED,
                                                            __HIP_MEMORY_SCOPE_AGENT);
                local += (double)BETA_ * (1.0 - nc / denom) * Lc;
            }
        }
        #pragma unroll
        for (int off = 32; off; off >>= 1) local += __shfl_down(local, off);
        if (t == 0) {
            const double ce = -__hip_atomic_load(gce, __ATOMIC_RELAXED,
                                                 __HIP_MEMORY_SCOPE_AGENT) / (double)nrows;
            out[0] = (float)(ce - local / (double)nrows);
        }
    }
}

extern "C" void kernel_launch(void* const* d_in, const int* in_sizes, int n_in,
                              void* d_out, int out_size, void* d_ws, size_t ws_size,
                              hipStream_t stream) {
    const float* y_pred = (const float*)d_in[0];
    const int*   y_true = (const int*)d_in[1];
    const int nrows = in_sizes[1];

    double*   gL   = (double*)d_ws;                        // 1024 B
    double*   gce  = (double*)((char*)d_ws + 1024);        // 8 B
    unsigned* gcnt = (unsigned*)((char*)d_ws + 1032);      // 512 B
    unsigned* done = (unsigned*)((char*)d_ws + 1544);      // 4 B

    zero_ws<<<dim3(1), dim3(256), 0, stream>>>((uint32_t*)d_ws);

    const int nblocks = 2048;
    loss_main<<<dim3(nblocks), dim3(256), 0, stream>>>(
        y_pred, y_true, gL, gcnt, gce, done, (float*)d_out, nrows, nblocks);
}

// Round 13
// 63.571 us; speedup vs baseline: 1.5508x; 1.5508x over previous
//
#include <hip/hip_runtime.h>
#include <math.h>
#include <stdint.h>

#define NCLS 128
constexpr float ALPHA = 0.5f;
constexpr float BETA_ = 0.5f;
constexpr float EPS_ = 1e-9f;

// ws: gL[128] double | gce double | gcnt[128] uint  = 1544 B
__global__ void zero_ws(uint32_t* __restrict__ ws) {
    const int t = threadIdx.x;               // 256 threads, 386 words
    if (t < 386) ws[t] = 0u;
    if (t + 256 < 386) ws[t + 256] = 0u;
}

// Streaming with explicit A/B register double-buffer: LOAD(next) is issued
// BEFORE COMPUTE(current), so each wave keeps 8 KB in flight during compute
// (breaks the burst->drain->compute convoy of rounds 1-12). 2 rows per 1 KB
// contiguous wave load (lanes 0-31 = even row, 32-63 = odd). No cross-lane
// broadcast: after the xor-reduce S is on ALL lanes -> logS computed wave-
// parallel; the label-owning lane adds tv into its own ce accumulator;
// contrib = log(e0 + eps*S) - logS  (label==0, *ALPHA)  /  log(S-e0+eps*S) - logS.
__global__ __launch_bounds__(256, 4) void loss_main(
    const float* __restrict__ y_pred,
    const int*   __restrict__ y_true,
    double* __restrict__ gL, unsigned* __restrict__ gcnt,
    double* __restrict__ gce, int nrows)
{
    __shared__ float    sL[NCLS];
    __shared__ unsigned scnt[NCLS];
    __shared__ float    sce;

    const int t = threadIdx.x;
    if (t == 0) sce = 0.f;
    if (t < NCLS) { sL[t] = 0.f; scnt[t] = 0u; }
    __syncthreads();

    const int lane = t & 63;
    const int half = lane >> 5;
    const int l32  = lane & 31;
    const int wgl  = blockIdx.x * 4 + (t >> 6);
    const int nW   = gridDim.x * 4;
    const int nPairs = nrows >> 1;
    const int step = nW * 8;

    float ce_local = 0.f;

    float4 A[8], B[8];
    int labA[8], labB[8];

    auto LOAD = [&](float4 (&V)[8], int (&L)[8], int pb) {
        const float* base = y_pred + ((size_t)(pb << 1) + half) * NCLS + (l32 << 2);
        #pragma unroll
        for (int u = 0; u < 8; ++u) {
            V[u] = *reinterpret_cast<const float4*>(base + (size_t)(u << 1) * NCLS);
            L[u] = y_true[((pb + u) << 1) + half];
        }
    };

    auto COMPUTE = [&](float4 (&V)[8], int (&L)[8]) {
        float S[8], e0[8];
        #pragma unroll
        for (int u = 0; u < 8; ++u) {
            const float ex = __expf(V[u].x), ey = __expf(V[u].y);
            const float ez = __expf(V[u].z), ew = __expf(V[u].w);
            e0[u] = ex;
            S[u]  = (ex + ey) + (ez + ew);
        }
        #pragma unroll
        for (int off = 16; off; off >>= 1) {
            #pragma unroll
            for (int u = 0; u < 8; ++u) S[u] += __shfl_xor(S[u], off);
        }
        #pragma unroll
        for (int u = 0; u < 8; ++u) {
            const float logS = __logf(S[u]);              // wave-parallel (S on all lanes)
            if ((L[u] >> 2) == l32) {                     // owning lane adds target logit
                const int ls = L[u] & 3;
                ce_local += (ls == 0) ? V[u].x : (ls == 1) ? V[u].y
                          : (ls == 2) ? V[u].z : V[u].w;
            }
            if (l32 == 0) {
                ce_local -= logS;
                const float contrib = (L[u] == 0)
                    ? ALPHA * (__logf(e0[u] + EPS_ * S[u]) - logS)
                    : (__logf((S[u] - e0[u]) + EPS_ * S[u]) - logS);
                atomicAdd(&sL[L[u]], contrib);
                atomicAdd(&scnt[L[u]], 1u);
            }
        }
    };

    int p = wgl * 8;
    if (p + 7 < nPairs) {
        LOAD(A, labA, p);
        while (true) {
            int pn = p + step;
            bool hn = (pn + 7 < nPairs);
            if (hn) LOAD(B, labB, pn);       // next batch in flight BEFORE compute
            COMPUTE(A, labA);
            p = pn;
            if (!hn) break;
            pn = p + step;
            hn = (pn + 7 < nPairs);
            if (hn) LOAD(A, labA, pn);
            COMPUTE(B, labB);
            p = pn;
            if (!hn) break;
        }
    }
    // residual singles: only this wave's (8-aligned) final partial chunk
    {
        const int qe = min(p + 8, nPairs);
        for (int q = p; q < qe; ++q) {
            const int row = (q << 1) + half;
            const float4 v = *reinterpret_cast<const float4*>(
                y_pred + (size_t)row * NCLS + (l32 << 2));
            const int lab = y_true[row];
            const float ex = __expf(v.x), ey = __expf(v.y);
            const float ez = __expf(v.z), ew = __expf(v.w);
            float S = (ex + ey) + (ez + ew);
            #pragma unroll
            for (int off = 16; off; off >>= 1) S += __shfl_xor(S, off);
            const float logS = __logf(S);
            if ((lab >> 2) == l32) {
                const int ls = lab & 3;
                ce_local += (ls == 0) ? v.x : (ls == 1) ? v.y : (ls == 2) ? v.z : v.w;
            }
            if (l32 == 0) {
                ce_local -= logS;
                const float contrib = (lab == 0)
                    ? ALPHA * (__logf(ex + EPS_ * S) - logS)
                    : (__logf((S - ex) + EPS_ * S) - logS);
                atomicAdd(&sL[lab], contrib);
                atomicAdd(&scnt[lab], 1u);
            }
        }
    }
    // odd last row: block 0, wave 0, half 0 lanes only
    if ((nrows & 1) && wgl == 0) {
        const int row = nrows - 1;
        const float4 v = *reinterpret_cast<const float4*>(
            y_pred + (size_t)row * NCLS + (l32 << 2));
        const int lab = y_true[row];
        if (half == 0) {
            const float ex = __expf(v.x), ey = __expf(v.y);
            const float ez = __expf(v.z), ew = __expf(v.w);
            float S = (ex + ey) + (ez + ew);
            #pragma unroll
            for (int off = 16; off; off >>= 1) S += __shfl_xor(S, off);
            const float logS = __logf(S);
            if ((lab >> 2) == l32) {
                const int ls = lab & 3;
                ce_local += (ls == 0) ? v.x : (ls == 1) ? v.y : (ls == 2) ? v.z : v.w;
            }
            if (l32 == 0) {
                ce_local -= logS;
                const float contrib = (lab == 0)
                    ? ALPHA * (__logf(ex + EPS_ * S) - logS)
                    : (__logf((S - ex) + EPS_ * S) - logS);
                atomicAdd(&sL[lab], contrib);
                atomicAdd(&scnt[lab], 1u);
            }
        }
    }

    float lp = ce_local;
    #pragma unroll
    for (int off = 32; off; off >>= 1) lp += __shfl_xor(lp, off);
    if (lane == 0) atomicAdd(&sce, lp);
    __syncthreads();

    if (t < NCLS) {
        const int c = (t + blockIdx.x) & (NCLS - 1);   // stagger contention
        if (scnt[c]) {
            atomicAdd(&gL[c], (double)sL[c]);
            atomicAdd(&gcnt[c], scnt[c]);
        }
    }
    if (t == 0) atomicAdd(gce, (double)sce);
}

__global__ void loss_final(const double* __restrict__ gL,
                           const unsigned* __restrict__ gcnt,
                           const double* __restrict__ gce,
                           float* __restrict__ out, int nrows)
{
    const int lane = threadIdx.x;   // 64 threads
    const double denom = (double)nrows - (double)gcnt[0];
    double local = 0.0;
    for (int c = lane; c < NCLS; c += 64) {
        if (c == 0) local += gL[0];                       // ALPHA already applied
        else        local += (double)BETA_ * (1.0 - (double)gcnt[c] / denom) * gL[c];
    }
    #pragma unroll
    for (int off = 32; off; off >>= 1) local += __shfl_down(local, off);
    if (lane == 0) {
        const double ce = -gce[0] / (double)nrows;
        out[0] = (float)(ce - local / (double)nrows);
    }
}

extern "C" void kernel_launch(void* const* d_in, const int* in_sizes, int n_in,
                              void* d_out, int out_size, void* d_ws, size_t ws_size,
                              hipStream_t stream) {
    const float* y_pred = (const float*)d_in[0];
    const int*   y_true = (const int*)d_in[1];
    const int nrows = in_sizes[1];

    double*   gL   = (double*)d_ws;                        // 1024 B
    double*   gce  = (double*)((char*)d_ws + 1024);        // 8 B
    unsigned* gcnt = (unsigned*)((char*)d_ws + 1032);      // 512 B

    zero_ws<<<dim3(1), dim3(256), 0, stream>>>((uint32_t*)d_ws);

    loss_main<<<dim3(1024), dim3(256), 0, stream>>>(y_pred, y_true, gL, gcnt, gce, nrows);
    loss_final<<<dim3(1), dim3(64), 0, stream>>>(gL, gcnt, gce, (float*)d_out, nrows);
}